// Round 4
// baseline (72.119 us; speedup 1.0000x reference)
//
#include <hip/hip_runtime.h>

// CutOut: images [B=64, H=512, W=512, C=3] fp32, NHWC.
// Zero a (2*half)x(2*half) square centered at (cy[b], cx[b]) per image.
//
// Streaming masked copy at the HBM roofline:
//  - one workgroup = 8 consecutive rows of one image (b uniform per block)
//  - 384 threads/block; each thread owns one float4 column-slot in each of
//    the 8 rows -> 8 back-to-back nt loads (8 KB in flight per wave), then
//    8 nt stores. Column predicates depend only on threadIdx -> computed
//    once, reused across rows. Row tests are scalar (uniform per block).
//  - non-temporal both directions: 402 MB streamed, zero reuse.

typedef float f32x4 __attribute__((ext_vector_type(4)));

__global__ __launch_bounds__(384) void cutout_rows8(
    const f32x4* __restrict__ in, f32x4* __restrict__ out,
    const int* __restrict__ cy, const int* __restrict__ cx,
    const int* __restrict__ len_p)
{
    const int blk = blockIdx.x;            // 0 .. B*H/8 - 1   (4096)
    const int b   = blk >> 6;              // 64 blocks per image (512/8)
    const int h0  = (blk & 63) << 3;       // first of 8 rows
    const int r4  = threadIdx.x;           // 0 .. 383 (float4 slot in row)
    const int gi0 = blk * 3072 + r4;       // 8 rows * 384 float4

    f32x4 v[8];
#pragma unroll
    for (int k = 0; k < 8; ++k)
        v[k] = __builtin_nontemporal_load(&in[gi0 + k * 384]);

    const int half = len_p[0] >> 1;        // uniform scalar
    const int ycy  = cy[b];                // uniform scalar (b block-uniform)
    const int lo_r = ycy - half, hi_r = ycy + half;

    if (h0 + 7 >= lo_r && h0 < hi_r) {     // any of the 8 rows in cutout?
        const int xcx = cx[b];
        const int lo = xcx - half, hi = xcx + half;
        const int base = r4 * 4;           // element k -> column (base+k)/3
        const bool c0 = ((base    ) / 3 >= lo) && ((base    ) / 3 < hi);
        const bool c1 = ((base + 1) / 3 >= lo) && ((base + 1) / 3 < hi);
        const bool c2 = ((base + 2) / 3 >= lo) && ((base + 2) / 3 < hi);
        const bool c3 = ((base + 3) / 3 >= lo) && ((base + 3) / 3 < hi);

#pragma unroll
        for (int k = 0; k < 8; ++k) {
            if (h0 + k >= lo_r && h0 + k < hi_r) {
                if (c0) v[k].x = 0.0f;
                if (c1) v[k].y = 0.0f;
                if (c2) v[k].z = 0.0f;
                if (c3) v[k].w = 0.0f;
            }
        }
    }

#pragma unroll
    for (int k = 0; k < 8; ++k)
        __builtin_nontemporal_store(v[k], &out[gi0 + k * 384]);
}

extern "C" void kernel_launch(void* const* d_in, const int* in_sizes, int n_in,
                              void* d_out, int out_size, void* d_ws, size_t ws_size,
                              hipStream_t stream) {
    const float* images = (const float*)d_in[0];
    const int*   cy     = (const int*)d_in[1];
    const int*   cx     = (const int*)d_in[2];
    const int*   len_p  = (const int*)d_in[3];

    const int B = 64, H = 512;
    const int grid  = (B * H) / 8;   // 4096 blocks, 8 rows each
    const int block = 384;

    cutout_rows8<<<grid, block, 0, stream>>>(
        (const f32x4*)images, (f32x4*)d_out, cy, cx, len_p);
}